// Round 13
// baseline (2224.406 us; speedup 1.0000x reference)
//
#include <hip/hip_runtime.h>
#include <hip/hip_bf16.h>

#define NB 128
#define LSEQ 512
#define HD 512
#define NI (NB * LSEQ)
#define GRID 256
#define GRPS 8
#define MTILE 512
#define MAXD 64

typedef __attribute__((ext_vector_type(8))) short bf16x8;
typedef __attribute__((ext_vector_type(4))) float f32x4;

static __device__ __forceinline__ unsigned f2b(float x) {
    union { __hip_bfloat16 b; unsigned short u; } cv;
    cv.b = __float2bfloat16(x);
    return (unsigned)cv.u;
}
static __device__ __forceinline__ float b2f(unsigned short u) {
    union { __hip_bfloat16 b; unsigned short u; } cv;
    cv.u = u;
    return __bfloat162float(cv.b);
}

// ---------------------------------------------------------------------------
// setup: h0 -> bf16, zero page, zero grid-barrier counter (every call: graph
// replays must start from a clean barrier state)
// ---------------------------------------------------------------------------
__global__ __launch_bounds__(256) void setup_kernel(
    const float* __restrict__ h0,
    unsigned short* __restrict__ h0bf, unsigned short* __restrict__ zeropage,
    int* __restrict__ barcnt)
{
    int i = blockIdx.x * 256 + threadIdx.x;
    if (i < NB * HD) h0bf[i] = (unsigned short)f2b(h0[i]);
    if (i < 1024) zeropage[i] = 0;
    if (i == 0) *barcnt = 0;
}

// ---------------------------------------------------------------------------
// pack: W [1536][512] row-major -> MFMA-B-frag-major bf16.
// lane l of frag (ct,kc) holds B[k=kc*32+(l>>4)*8+j][col=ct*16+(l&15)], j=0..7
// element index: ((ct*16+kc)*64 + lane)*8 + j ; ct = global col/16 (0..95)
// ---------------------------------------------------------------------------
__global__ __launch_bounds__(256) void pack_kernel(
    const float* __restrict__ W_ih, const float* __restrict__ W_hh,
    unsigned short* __restrict__ Xpack, unsigned short* __restrict__ Hpack)
{
    int idx = blockIdx.x * 256 + threadIdx.x;   // = g*512 + k
    if (idx >= 1536 * 512) return;
    int g = idx >> 9, k = idx & 511;
    int ct = g >> 4, lane_lo = g & 15;
    int kc = k >> 5, kin = k & 31;
    int lane = (kin >> 3) * 16 + lane_lo;
    int j = kin & 7;
    int p = ((ct * 16 + kc) * 64 + lane) * 8 + j;
    Xpack[p] = (unsigned short)f2b(W_ih[idx]);
    Hpack[p] = (unsigned short)f2b(W_hh[idx]);
}

// ---------------------------------------------------------------------------
// sched: serial per-row scan (proven). counts/offsets per depth;
// pos_of[n*L+l]; prevoff[pos] = prev hperm elem offset (>=0) | -1 (zero h)
// | -(n*512+2) (h0 row n); ndepth = max depth + 1.
// ---------------------------------------------------------------------------
__global__ __launch_bounds__(128) void sched_kernel(
    const int* __restrict__ is_init,
    int* __restrict__ counts_g, int* __restrict__ offsets_g,
    int* __restrict__ pos_of, int* __restrict__ prevoff,
    int* __restrict__ ndepth_g)
{
    __shared__ int cnt[LSEQ];
    __shared__ int off[LSEQ];
    __shared__ int ndmax;
    int tid = threadIdx.x;
    for (int i = tid; i < LSEQ; i += 128) cnt[i] = 0;
    if (tid == 0) ndmax = 1;
    __syncthreads();
    {
        int d = 0, dm = 0;
        for (int l = 0; l < LSEQ; l++) {
            int ii = is_init[tid * LSEQ + l];
            d = ii ? 0 : (l == 0 ? 0 : d + 1);
            if (d > dm) dm = d;
            atomicAdd(&cnt[d], 1);
        }
        atomicMax(&ndmax, dm + 1);
    }
    __syncthreads();
    if (tid == 0) {
        int acc = 0;
        for (int i = 0; i < LSEQ; i++) { off[i] = acc; acc += cnt[i]; }
        *ndepth_g = ndmax;
    }
    __syncthreads();
    for (int i = tid; i < LSEQ; i += 128) {
        counts_g[i] = cnt[i];
        offsets_g[i] = off[i];
        cnt[i] = 0;
    }
    __syncthreads();
    {
        int d = 0;
        int prevpos = 0;
        for (int l = 0; l < LSEQ; l++) {
            int ii = is_init[tid * LSEQ + l];
            d = ii ? 0 : (l == 0 ? 0 : d + 1);
            int pos = off[d] + atomicAdd(&cnt[d], 1);
            pos_of[tid * LSEQ + l] = pos;
            int pr;
            if (d == 0) pr = ii ? -1 : -(tid * 512 + 2);
            else pr = prevpos * 512;
            prevoff[pos] = pr;
            prevpos = pos;
        }
    }
}

// ---------------------------------------------------------------------------
// xcvt: inp f32 -> xbf bf16 in POS ORDER (row i -> row pos_of[i]); the
// persistent kernel's phase-X reads become pure contiguous streams.
// ---------------------------------------------------------------------------
__global__ __launch_bounds__(256) void xcvt_kernel(
    const float* __restrict__ inp, const int* __restrict__ pos_of,
    unsigned short* __restrict__ xbf)
{
    size_t idx = (size_t)blockIdx.x * 256 + threadIdx.x;
    int row = (int)(idx >> 6);            // item index (n*L+l)
    int c8 = (int)(idx & 63);             // 8-elem chunk within row
    const float* src = inp + (size_t)row * 512 + c8 * 8;
    float4 v0 = *(const float4*)(src);
    float4 v1 = *(const float4*)(src + 4);
    uint4 u;
    u.x = f2b(v0.x) | (f2b(v0.y) << 16);
    u.y = f2b(v0.z) | (f2b(v0.w) << 16);
    u.z = f2b(v1.x) | (f2b(v1.y) << 16);
    u.w = f2b(v1.z) | (f2b(v1.w) << 16);
    size_t pos = (size_t)pos_of[row];
    *(uint4*)(xbf + pos * 512 + c8 * 8) = u;
}

// ---------------------------------------------------------------------------
// grid barrier: arrive (release-fence + atomic inc), tid0 spins to target,
// then block-wide acquire-fence. Device-scope fences handle cross-XCD L2
// non-coherence. All 256 blocks are guaranteed co-resident (48KB LDS,
// <=256 VGPR, 8 waves -> >=1 block/CU capacity).
// ---------------------------------------------------------------------------
static __device__ __forceinline__ void gbar(int* cnt, int target) {
    __syncthreads();
    __threadfence();                       // release: my writes visible device-wide
    if (threadIdx.x == 0) {
        atomicAdd(cnt, 1);
        while (atomicAdd(cnt, 0) < target) { __builtin_amdgcn_s_sleep(1); }
    }
    __syncthreads();
    __threadfence();                       // acquire: see others' writes
}

// ---------------------------------------------------------------------------
// persist: ONE kernel for gx GEMM + all depth phases.
// Grid 256 = 32 slices x 8 grps; bid%8 = grp -> all 32 slices of a tile-group
// share one XCD's L2 (A-row re-reads are L2-local).
// Phase X: Xpack slice (48 KB) in LDS once; gx for all NI pos-ordered items
//   (contiguous xbf reads, no gather) -> gxp bf16 [NI][1536].
// Phase H: Hpack slice in LDS once; per depth d: h-side GEMM (hprev gather
//   via prevoff) + fused GRU epilogue reading gxp; grid barrier per depth.
// Per wave per k-step: 4 A-loads : 3 ds_read_b128 : 12 MFMA. acc 12 f32x4.
// ---------------------------------------------------------------------------
__global__ __launch_bounds__(512, 2) void persist_kernel(
    const unsigned short* __restrict__ Xpack, const unsigned short* __restrict__ Hpack,
    const float* __restrict__ b_ih, const float* __restrict__ b_hh,
    const int* __restrict__ counts, const int* __restrict__ offsets,
    const int* __restrict__ prevoff,
    const unsigned short* __restrict__ xbf,
    unsigned short* __restrict__ gxp,
    const unsigned short* __restrict__ h0bf, const unsigned short* __restrict__ zeropage,
    unsigned short* __restrict__ hperm,
    const int* __restrict__ ndepth_g, int* __restrict__ barcnt)
{
    const int slice = blockIdx.x >> 3;
    const int grp = blockIdx.x & 7;
    const int tid = threadIdx.x;
    const int w = tid >> 6, lane = tid & 63;
    const int l15 = lane & 15, lhi = lane >> 4;
    const int col = slice * 16 + l15;
    const int nd0 = *ndepth_g;
    const int nd = (nd0 < MAXD) ? nd0 : MAXD;

    __shared__ unsigned short Wl[3 * 16 * 512];   // 48 KB

    // ================= Phase X: gx = x @ W_ih^T + b_ih =================
    #pragma unroll
    for (int i = 0; i < 6; ++i) {
        int q = tid + i * 512;            // uint4 index, 3072 total
        int g = q >> 10, rem = q & 1023;
        ((uint4*)Wl)[q] = *((const uint4*)(Xpack + (size_t)(g * 32 + slice) * 8192) + rem);
    }
    const float bxR = b_ih[col];
    const float bxZ = b_ih[512 + col];
    const float bxN = b_ih[1024 + col];
    __syncthreads();

    for (int tile = grp; tile < NI / MTILE; tile += GRPS) {
        const unsigned short* xp[4];
        #pragma unroll
        for (int f = 0; f < 4; ++f)
            xp[f] = xbf + (size_t)(tile * MTILE + w * 64 + f * 16 + l15) * 512;

        f32x4 aR[4], aZ[4], aN[4];
        #pragma unroll
        for (int f = 0; f < 4; ++f) {
            aR[f] = (f32x4){bxR, bxR, bxR, bxR};
            aZ[f] = (f32x4){bxZ, bxZ, bxZ, bxZ};
            aN[f] = (f32x4){bxN, bxN, bxN, bxN};
        }

        #pragma unroll 4
        for (int ks = 0; ks < 16; ++ks) {
            bf16x8 bRv = *(const bf16x8*)(Wl + (0 * 16 + ks) * 512 + lane * 8);
            bf16x8 bZv = *(const bf16x8*)(Wl + (1 * 16 + ks) * 512 + lane * 8);
            bf16x8 bNv = *(const bf16x8*)(Wl + (2 * 16 + ks) * 512 + lane * 8);
            #pragma unroll
            for (int f = 0; f < 4; ++f) {
                bf16x8 a = *(const bf16x8*)(xp[f] + lhi * 8 + ks * 32);
                aR[f] = __builtin_amdgcn_mfma_f32_16x16x32_bf16(a, bRv, aR[f], 0, 0, 0);
                aZ[f] = __builtin_amdgcn_mfma_f32_16x16x32_bf16(a, bZv, aZ[f], 0, 0, 0);
                aN[f] = __builtin_amdgcn_mfma_f32_16x16x32_bf16(a, bNv, aN[f], 0, 0, 0);
            }
        }

        // write gx rows (C/D: item=(lane>>4)*4+v, col=lane&15)
        #pragma unroll
        for (int f = 0; f < 4; ++f) {
            #pragma unroll
            for (int v = 0; v < 4; ++v) {
                size_t pos = (size_t)(tile * MTILE + w * 64 + f * 16 + lhi * 4 + v);
                unsigned short* gp = gxp + pos * 1536 + col;
                gp[0]    = (unsigned short)f2b(aR[f][v]);
                gp[512]  = (unsigned short)f2b(aZ[f][v]);
                gp[1024] = (unsigned short)f2b(aN[f][v]);
            }
        }
    }

    int gen = 1;
    gbar(barcnt, gen * GRID);

    // ================= Phase H: depth phases =================
    #pragma unroll
    for (int i = 0; i < 6; ++i) {
        int q = tid + i * 512;
        int g = q >> 10, rem = q & 1023;
        ((uint4*)Wl)[q] = *((const uint4*)(Hpack + (size_t)(g * 32 + slice) * 8192) + rem);
    }
    const float bhR = b_hh[col];
    const float bhZ = b_hh[512 + col];
    const float bhN = b_hh[1024 + col];
    __syncthreads();

    for (int d = 0; d < nd; ++d) {
        const int count = counts[d];
        const int base = offsets[d];
        const int ntiles = (count + MTILE - 1) >> 9;

        for (int tile = grp; tile < ntiles; tile += GRPS) {
            const unsigned short* hp[4];
            #pragma unroll
            for (int f = 0; f < 4; ++f) {
                int row = tile * MTILE + w * 64 + f * 16 + l15;
                if (row < count) {
                    int off = prevoff[base + row];
                    hp[f] = (off >= 0) ? (hperm + off)
                          : (off == -1 ? zeropage : (h0bf + (-off - 2)));
                } else {
                    hp[f] = zeropage;
                }
            }

            f32x4 aR[4], aZ[4], aN[4];
            #pragma unroll
            for (int f = 0; f < 4; ++f) {
                aR[f] = (f32x4){bhR, bhR, bhR, bhR};
                aZ[f] = (f32x4){bhZ, bhZ, bhZ, bhZ};
                aN[f] = (f32x4){bhN, bhN, bhN, bhN};
            }

            #pragma unroll 4
            for (int ks = 0; ks < 16; ++ks) {
                bf16x8 bRv = *(const bf16x8*)(Wl + (0 * 16 + ks) * 512 + lane * 8);
                bf16x8 bZv = *(const bf16x8*)(Wl + (1 * 16 + ks) * 512 + lane * 8);
                bf16x8 bNv = *(const bf16x8*)(Wl + (2 * 16 + ks) * 512 + lane * 8);
                #pragma unroll
                for (int f = 0; f < 4; ++f) {
                    bf16x8 a = *(const bf16x8*)(hp[f] + lhi * 8 + ks * 32);
                    aR[f] = __builtin_amdgcn_mfma_f32_16x16x32_bf16(a, bRv, aR[f], 0, 0, 0);
                    aZ[f] = __builtin_amdgcn_mfma_f32_16x16x32_bf16(a, bZv, aZ[f], 0, 0, 0);
                    aN[f] = __builtin_amdgcn_mfma_f32_16x16x32_bf16(a, bNv, aN[f], 0, 0, 0);
                }
            }

            // epilogue: GRU pointwise
            #pragma unroll
            for (int f = 0; f < 4; ++f) {
                #pragma unroll
                for (int v = 0; v < 4; ++v) {
                    int row = tile * MTILE + w * 64 + f * 16 + lhi * 4 + v;
                    if (row >= count) continue;
                    size_t pos = (size_t)(base + row);
                    int off = prevoff[pos];
                    const unsigned short* hpp = (off >= 0) ? (hperm + off)
                        : (off == -1 ? zeropage : (h0bf + (-off - 2)));
                    float hprev = b2f(hpp[col]);
                    const unsigned short* gp = gxp + pos * 1536 + col;
                    float r = 1.f / (1.f + __expf(-(b2f(gp[0]) + aR[f][v])));
                    float z = 1.f / (1.f + __expf(-(b2f(gp[512]) + aZ[f][v])));
                    float nn = tanhf(b2f(gp[1024]) + r * aN[f][v]);
                    hperm[pos * 512 + col] = (unsigned short)f2b((1.f - z) * nn + z * hprev);
                }
            }
        }

        if (d + 1 < nd) {
            ++gen;
            gbar(barcnt, gen * GRID);
        }
    }
}

// ---------------------------------------------------------------------------
// hlast: h[n, L-1, :] -> fp32 ws (via pos_of; before hexp overwrites hperm)
// ---------------------------------------------------------------------------
__global__ __launch_bounds__(256) void hlast_kernel(
    const unsigned short* __restrict__ hperm, const int* __restrict__ pos_of,
    float* __restrict__ hlast)
{
    int i = blockIdx.x * 256 + threadIdx.x;
    if (i >= NB * HD) return;
    int n = i >> 9, c = i & 511;
    size_t pos = (size_t)pos_of[n * LSEQ + (LSEQ - 1)];
    hlast[i] = b2f(hperm[pos * HD + c]);
}

// ---------------------------------------------------------------------------
// LayerNorm: out1[n,l] = LN(hperm[pos_of[n,l]] + inp[n,l]) * gamma + beta
// ---------------------------------------------------------------------------
__global__ __launch_bounds__(256) void ln_kernel(
    const unsigned short* __restrict__ hperm, const int* __restrict__ pos_of,
    const float* __restrict__ inp,
    const float* __restrict__ gamma, const float* __restrict__ beta,
    float* __restrict__ out1)
{
    size_t row = blockIdx.x;
    int tid = threadIdx.x;
    int c = tid * 2;
    size_t pos = (size_t)pos_of[row];
    const unsigned short* yrow = hperm + pos * HD;
    const float* xrow = inp + row * HD;
    ushort2 yv = *(const ushort2*)(yrow + c);
    float2 xv = *(const float2*)(xrow + c);
    float a = b2f(yv.x) + xv.x;
    float b = b2f(yv.y) + xv.y;
    float s = a + b, ss = a * a + b * b;
    #pragma unroll
    for (int m = 1; m < 64; m <<= 1) {
        s  += __shfl_xor(s, m, 64);
        ss += __shfl_xor(ss, m, 64);
    }
    __shared__ float ps[4], pss[4];
    int w = tid >> 6;
    if ((tid & 63) == 0) { ps[w] = s; pss[w] = ss; }
    __syncthreads();
    s  = ps[0] + ps[1] + ps[2] + ps[3];
    ss = pss[0] + pss[1] + pss[2] + pss[3];
    float mu = s * (1.f / 512.f);
    float var = ss * (1.f / 512.f) - mu * mu;
    float inv = rsqrtf(var + 1e-5f);
    float2 gv = *(const float2*)(gamma + c);
    float2 bv = *(const float2*)(beta + c);
    float2 o;
    o.x = (a - mu) * inv * gv.x + bv.x;
    o.y = (b - mu) * inv * gv.y + bv.y;
    *(float2*)(out1 + row * HD + c) = o;
}

// ---------------------------------------------------------------------------
// hexp: out2[n,l,:] = hlast[n,:]  (overwrites gxp tail + hperm; runs last)
// ---------------------------------------------------------------------------
__global__ __launch_bounds__(256) void hexp_kernel(
    const float* __restrict__ hlast, float* __restrict__ out2)
{
    size_t idx = (size_t)blockIdx.x * 256 + threadIdx.x;   // float4 units
    if (idx >= (size_t)NI * HD / 4) return;
    int per_n = LSEQ * HD / 4;
    int n = (int)(idx / per_n);
    int c4 = (int)(idx & (HD / 4 - 1));
    float4 v = *(const float4*)(hlast + n * HD + c4 * 4);
    *(float4*)(out2 + idx * 4) = v;
}

// ---------------------------------------------------------------------------
extern "C" void kernel_launch(void* const* d_in, const int* in_sizes, int n_in,
                              void* d_out, int out_size, void* d_ws, size_t ws_size,
                              hipStream_t stream)
{
    const float* inp   = (const float*)d_in[0];
    const float* h0    = (const float*)d_in[1];
    const int*  is_ini = (const int*)d_in[2];
    const float* W_ih  = (const float*)d_in[3];
    const float* W_hh  = (const float*)d_in[4];
    const float* b_ih  = (const float*)d_in[5];
    const float* b_hh  = (const float*)d_in[6];
    const float* gamma = (const float*)d_in[7];
    const float* beta  = (const float*)d_in[8];

    const size_t NLH = (size_t)NI * HD;            // 33,554,432
    float* out1 = (float*)d_out;
    float* out2 = out1 + NLH;
    // d_out overlay (268.4 MB exactly):
    //   gxp        bf16 [NI][1536] = 201.3 MB at offset 0       (dead after persist)
    //   xbf/hperm  bf16 [NI][512]  =  67.1 MB at offset 201.3
    //     (xbf written by xcvt, fully consumed in persist phase X;
    //      hperm written in phase H, read by hlast/ln; hexp overwrites last)
    unsigned short* gxp   = (unsigned short*)d_out;
    unsigned short* hperm = gxp + (size_t)NI * 1536;
    unsigned short* xbf   = hperm;

    unsigned short* Xpack = (unsigned short*)d_ws;            // 1.5 MB
    unsigned short* Hpack = Xpack + 1536 * 512;               // 1.5 MB
    int* counts  = (int*)(Hpack + 1536 * 512);                // 2 KB
    int* offsets = counts + LSEQ;                             // 2 KB
    int* pos_of  = offsets + LSEQ;                            // 256 KB
    int* prevoff = pos_of + NI;                               // 256 KB
    int* ndepth_g = prevoff + NI;                             // 4 B
    int* barcnt  = ndepth_g + 64;                             // 4 B (own line)
    unsigned short* h0bf = (unsigned short*)(barcnt + 64);    // 128 KB
    unsigned short* zeropage = h0bf + NB * HD;                // 2 KB
    float* hlast = (float*)(zeropage + 1024);                 // 256 KB

    setup_kernel<<<(NB * HD + 255) / 256, 256, 0, stream>>>(h0, h0bf, zeropage, barcnt);
    pack_kernel<<<(1536 * 512 + 255) / 256, 256, 0, stream>>>(W_ih, W_hh, Xpack, Hpack);
    sched_kernel<<<1, 128, 0, stream>>>(is_ini, counts, offsets, pos_of, prevoff, ndepth_g);

    xcvt_kernel<<<(int)(NLH / 8 / 256), 256, 0, stream>>>(inp, pos_of, xbf);

    persist_kernel<<<GRID, 512, 0, stream>>>(
        Xpack, Hpack, b_ih, b_hh, counts, offsets, prevoff,
        xbf, gxp, h0bf, zeropage, hperm, ndepth_g, barcnt);

    hlast_kernel<<<(NB * HD + 255) / 256, 256, 0, stream>>>(hperm, pos_of, hlast);
    ln_kernel<<<NI, 256, 0, stream>>>(hperm, pos_of, inp, gamma, beta, out1);
    hexp_kernel<<<(int)(NLH / 4 / 256), 256, 0, stream>>>(hlast, out2);
}